// Round 17
// baseline (299.564 us; speedup 1.0000x reference)
//
#include <hip/hip_runtime.h>

typedef __attribute__((ext_vector_type(8))) short bf16x8;
typedef __attribute__((ext_vector_type(4))) float f32x4;

#define D_MODEL 1024
#define T_LEN 2048
#define BATCH 2
#define N_HEADS 16
#define D_HEAD 64
#define WINDOW 256
#define N_STATE 128
#define D_FF 4096
#define N_CAT 4224   // 4*D_MODEL + N_STATE
#define LDQ 4352     // N_CAT padded
#define M_ROWS 4096  // B*T

static __device__ __forceinline__ float bf2f(unsigned short u) {
  union { unsigned int i; float f; } v; v.i = ((unsigned int)u) << 16; return v.f;
}
static __device__ __forceinline__ unsigned short f2bf(float f) {
  unsigned int x = __float_as_uint(f);
  return (unsigned short)((x + 0x7FFFu + ((x >> 16) & 1u)) >> 16);
}

static __device__ __forceinline__ void gl_lds16(const void* g, void* l) {
  __builtin_amdgcn_global_load_lds(
      (const __attribute__((address_space(1))) unsigned int*)g,
      (__attribute__((address_space(3))) unsigned int*)l, 16, 0, 0);
}

// ---------------------------------------------------------------------------
// prep_kernel: all weight transposes (f32->bf16) + bias concat in ONE launch.
// ---------------------------------------------------------------------------
__global__ __launch_bounds__(256) void prep_kernel(
    const float* __restrict__ wq, const float* __restrict__ wk,
    const float* __restrict__ wv, const float* __restrict__ wg,
    const float* __restrict__ wo, const float* __restrict__ Bw,
    const float* __restrict__ Cw, const float* __restrict__ w1,
    const float* __restrict__ w2,
    const float* __restrict__ bq, const float* __restrict__ bk,
    const float* __restrict__ bv, const float* __restrict__ bg,
    unsigned short* __restrict__ WcatT, unsigned short* __restrict__ woT,
    unsigned short* __restrict__ CwT, unsigned short* __restrict__ w1T,
    unsigned short* __restrict__ w2T, float* __restrict__ bcat)
{
  const int bid = blockIdx.x;
  if (bid >= 13568) {
    const int i = (bid - 13568) * 256 + threadIdx.x;
    if (i < LDQ) {
      float v = 0.0f;
      if (i < 1024)      v = bq[i];
      else if (i < 2048) v = bk[i - 1024];
      else if (i < 3072) v = bv[i - 2048];
      else if (i < 4096) v = bg[i - 3072];
      bcat[i] = v;
    }
    return;
  }
  const float* src; unsigned short* dst;
  int N, n_off, ldd, x, y;
  if (bid < 5120) {
    const int z = bid >> 10, t = bid & 1023;
    x = t & 31; y = t >> 5;
    src = (z == 0) ? wq : (z == 1) ? wk : (z == 2) ? wv : (z == 3) ? wg : wo;
    dst = (z < 4) ? WcatT : woT;
    n_off = (z < 4) ? z * 1024 : 0;
    N = 1024; ldd = 1024;
  } else if (bid < 5248) {
    const int t = bid - 5120; x = t & 31; y = t >> 5;
    src = Bw; dst = WcatT; n_off = 4096; N = 128; ldd = 1024;
  } else if (bid < 5376) {
    const int t = bid - 5248; x = t & 3; y = t >> 2;
    src = Cw; dst = CwT; n_off = 0; N = 1024; ldd = 128;
  } else if (bid < 9472) {
    const int t = bid - 5376; x = t & 31; y = t >> 5;
    src = w1; dst = w1T; n_off = 0; N = 4096; ldd = 1024;
  } else {
    const int t = bid - 9472; x = t & 127; y = t >> 7;
    src = w2; dst = w2T; n_off = 0; N = 1024; ldd = 4096;
  }
  __shared__ float tile[32][33];
  const int kt = x * 32, nt = y * 32;
  const int c = threadIdx.x & 31, r0 = threadIdx.x >> 5;
#pragma unroll
  for (int i = 0; i < 4; i++) {
    const int r = r0 + i * 8;
    tile[r][c] = src[(size_t)(kt + r) * N + nt + c];
  }
  __syncthreads();
#pragma unroll
  for (int i = 0; i < 4; i++) {
    const int r = r0 + i * 8;
    dst[(size_t)(n_off + nt + r) * ldd + kt + c] = f2bf(tile[c][r]);
  }
}

// ---------------------------------------------------------------------------
// qkv pack: head-contiguous copies of Q,K + transposed V.
//   y=0: Qp[bh][t][d] = qkvgu[.. h*64+d]          (coalesced copy)
//   y=1: Kp[bh][t][d] = qkvgu[.. 1024+h*64+d]     (coalesced copy)
//   y=2: VT[bh][d][t] = qkvgu[.. 2048+h*64+d]     (32x64 transpose)
// ---------------------------------------------------------------------------
__global__ __launch_bounds__(256) void qkvpack_kernel(
    const unsigned short* __restrict__ qkvgu, unsigned short* __restrict__ Qp,
    unsigned short* __restrict__ Kp, unsigned short* __restrict__ VT)
{
  const int bh = blockIdx.z;
  const int b = bh >> 4, h = bh & 15;
  const int t0 = blockIdx.x * 32;
  const int tid = threadIdx.x;
  if (blockIdx.y < 2) {
    unsigned short* dst = (blockIdx.y == 0) ? Qp : Kp;
    const int off = (blockIdx.y == 0) ? 0 : 1024;
    const int t = tid >> 3, c = (tid & 7) * 8;
    const uint4 d = *(const uint4*)(qkvgu + ((size_t)b * T_LEN + t0 + t) * LDQ + off + h * 64 + c);
    *(uint4*)(dst + ((size_t)bh * T_LEN + t0 + t) * 64 + c) = d;
    return;
  }
  __shared__ unsigned short tile[32][65];
  const int c = tid & 63, r0 = tid >> 6;
#pragma unroll
  for (int i = 0; i < 8; i++) {
    const int r = r0 + i * 4;
    tile[r][c] = qkvgu[((size_t)b * T_LEN + t0 + r) * LDQ + 2048 + h * 64 + c];
  }
  __syncthreads();
  // write: 64 d-rows x 32 t-cols
  const int dd = tid >> 2, cc = (tid & 3) * 8;
#pragma unroll
  for (int i = 0; i < 8; i++) {
    if (i == 0) {
      ushort a0 = tile[cc + 0][dd], a1 = tile[cc + 1][dd], a2 = tile[cc + 2][dd], a3 = tile[cc + 3][dd];
      ushort a4 = tile[cc + 4][dd], a5 = tile[cc + 5][dd], a6 = tile[cc + 6][dd], a7 = tile[cc + 7][dd];
      ushort4 w0 = {a0, a1, a2, a3}, w1 = {a4, a5, a6, a7};
      unsigned short* wp = VT + ((size_t)bh * 64 + dd) * T_LEN + t0 + cc;
      *(ushort4*)wp = w0;
      *(ushort4*)(wp + 4) = w1;
    }
  }
}

// ---------------------------------------------------------------------------
// LayerNorm (LN1)
// ---------------------------------------------------------------------------
__global__ __launch_bounds__(256) void ln_kernel(
    const float* __restrict__ x, const float* __restrict__ g,
    const float* __restrict__ b, unsigned short* __restrict__ out)
{
  const int row = blockIdx.x, tid = threadIdx.x;
  const float4 xv = ((const float4*)(x + (size_t)row * 1024))[tid];
  float s  = xv.x + xv.y + xv.z + xv.w;
  float s2 = xv.x * xv.x + xv.y * xv.y + xv.z * xv.z + xv.w * xv.w;
#pragma unroll
  for (int off = 32; off >= 1; off >>= 1) {
    s  += __shfl_down(s, off);
    s2 += __shfl_down(s2, off);
  }
  __shared__ float red[8];
  const int wave = tid >> 6;
  if ((tid & 63) == 0) { red[wave] = s; red[4 + wave] = s2; }
  __syncthreads();
  s  = red[0] + red[1] + red[2] + red[3];
  s2 = red[4] + red[5] + red[6] + red[7];
  const float mu = s * (1.0f / 1024.0f);
  const float rs = rsqrtf(s2 * (1.0f / 1024.0f) - mu * mu + 1e-5f);
  const float4 gv = ((const float4*)g)[tid];
  const float4 bv = ((const float4*)b)[tid];
  ushort4 o;
  o.x = f2bf((xv.x - mu) * rs * gv.x + bv.x);
  o.y = f2bf((xv.y - mu) * rs * gv.y + bv.y);
  o.z = f2bf((xv.z - mu) * rs * gv.z + bv.z);
  o.w = f2bf((xv.w - mu) * rs * gv.w + bv.w);
  ((ushort4*)(out + (size_t)row * 1024))[tid] = o;
}

// ---------------------------------------------------------------------------
// gemm128ho (r12-verified): 128x128, BK=64, 4 blocks/CU, GROUP_M=8 + XCD
// swizzle, LDS-staged bf16 epilogue.
// ---------------------------------------------------------------------------
template<int ACT>
__global__ __launch_bounds__(256, 4) void gemm128ho(
    const unsigned short* __restrict__ A, const unsigned short* __restrict__ BT,
    const float* __restrict__ bias, unsigned short* __restrict__ C,
    int ldc, int K, int nby)
{
  __shared__ char smem[32768];
  char* const As = smem;
  char* const Bs = smem + 16384;
  const int nwg = gridDim.x;
  int bid = blockIdx.x;
  {
    const int q = nwg >> 3, r = nwg & 7, xx = bid & 7, o = bid >> 3;
    bid = (xx < r ? xx * (q + 1) : r * (q + 1) + (xx - r) * q) + o;
  }
  const int per_group = 8 * nby;
  const int grp = bid / per_group, rem = bid % per_group;
  const int m0 = (grp * 8 + (rem & 7)) * 128;
  const int n0 = (rem >> 3) * 128;

  const int tid = threadIdx.x, lane = tid & 63, wave = tid >> 6;
  const int l15 = lane & 15, lg = lane >> 4;
  const int wm = (wave >> 1) * 64, wn = (wave & 1) * 64;
  f32x4 acc[4][4];
#pragma unroll
  for (int i = 0; i < 4; i++)
#pragma unroll
    for (int j = 0; j < 4; j++) acc[i][j] = (f32x4){0.f, 0.f, 0.f, 0.f};

  const char* srcA[4]; const char* srcB[4];
#pragma unroll
  for (int j = 0; j < 4; j++) {
    const int p = j * 4096 + tid * 16;
    const int R = p >> 7;
    const int cb = (p & 127) ^ ((R & 7) << 4);
    srcA[j] = (const char*)A  + (size_t)(m0 + R) * (size_t)(K * 2) + cb;
    srcB[j] = (const char*)BT + (size_t)(n0 + R) * (size_t)(K * 2) + cb;
  }

  const int NT = K >> 6;
  for (int t = 0; t < NT; ++t) {
    __syncthreads();
#pragma unroll
    for (int j = 0; j < 4; j++) {
      gl_lds16(srcA[j] + (size_t)t * 128, As + j * 4096 + tid * 16);
      gl_lds16(srcB[j] + (size_t)t * 128, Bs + j * 4096 + tid * 16);
    }
    __syncthreads();
    bf16x8 af[4][2], bfr[4][2];
#pragma unroll
    for (int mf = 0; mf < 4; mf++)
#pragma unroll
      for (int ks = 0; ks < 2; ks++) {
        const int R = wm + mf * 16 + l15;
        af[mf][ks] = *(const bf16x8*)(As + (R << 7) + ((ks * 64 + lg * 16) ^ ((R & 7) << 4)));
      }
#pragma unroll
    for (int nf = 0; nf < 4; nf++)
#pragma unroll
      for (int ks = 0; ks < 2; ks++) {
        const int R = wn + nf * 16 + l15;
        bfr[nf][ks] = *(const bf16x8*)(Bs + (R << 7) + ((ks * 64 + lg * 16) ^ ((R & 7) << 4)));
      }
#pragma unroll
    for (int mf = 0; mf < 4; mf++)
#pragma unroll
      for (int nf = 0; nf < 4; nf++)
#pragma unroll
        for (int ks = 0; ks < 2; ks++)
          acc[mf][nf] = __builtin_amdgcn_mfma_f32_16x16x32_bf16(
              af[mf][ks], bfr[nf][ks], acc[mf][nf], 0, 0, 0);
  }

  __syncthreads();
  unsigned short (*Ct)[128] = (unsigned short(*)[128])smem;
#pragma unroll
  for (int nf = 0; nf < 4; nf++) {
    const int col = wn + nf * 16 + l15;
    const float bv = bias[n0 + col];
#pragma unroll
    for (int mf = 0; mf < 4; mf++) {
      const int rbase = wm + mf * 16 + lg * 4;
#pragma unroll
      for (int r = 0; r < 4; r++) {
        float v = acc[mf][nf][r] + bv;
        if (ACT == 2) v = 0.5f * v * (1.0f + erff(v * 0.70710678118654752f));
        Ct[rbase + r][col] = f2bf(v);
      }
    }
  }
  __syncthreads();
#pragma unroll
  for (int pass = 0; pass < 8; pass++) {
    const int idx = pass * 256 + tid;
    const int row = idx >> 4, c8 = (idx & 15) * 8;
    const uint4 d = *(const uint4*)&Ct[row][c8];
    *(uint4*)(C + (size_t)(m0 + row) * ldc + n0 + c8) = d;
  }
}

// ---------------------------------------------------------------------------
// gemm_ho (r10-verified): 128x64, 4 blocks/CU; bf16-LDS epilogue / f32+resid
// ---------------------------------------------------------------------------
template<int ACT, bool OUT_BF16, bool RESID>
__global__ __launch_bounds__(256, 4) void gemm_ho(
    const unsigned short* __restrict__ A, const unsigned short* __restrict__ BT,
    const float* __restrict__ bias, const float* __restrict__ resid,
    void* __restrict__ Cout, int ldc, int K, int nbx)
{
  __shared__ char As[16384];
  __shared__ char Bs[8192];
  const int nwg = gridDim.x;
  int bid = blockIdx.x;
  {
    const int q = nwg >> 3, r = nwg & 7, xx = bid & 7, o = bid >> 3;
    bid = (xx < r ? xx * (q + 1) : r * (q + 1) + (xx - r) * q) + o;
  }
  const int m0 = (bid % nbx) * 128;
  const int n0 = (bid / nbx) * 64;
  const int tid = threadIdx.x, lane = tid & 63, wave = tid >> 6;
  const int l15 = lane & 15, lg = lane >> 4;
  const int wm = (wave & 1) * 64, wn = (wave >> 1) * 32;
  f32x4 acc[4][2];
#pragma unroll
  for (int i = 0; i < 4; i++)
#pragma unroll
    for (int j = 0; j < 2; j++) acc[i][j] = (f32x4){0.f, 0.f, 0.f, 0.f};

  const char* srcA[4]; const char* srcB[2];
#pragma unroll
  for (int j = 0; j < 4; j++) {
    const int p = j * 4096 + tid * 16;
    const int R = p >> 7;
    const int cb = (p & 127) ^ ((R & 7) << 4);
    srcA[j] = (const char*)A + (size_t)(m0 + R) * (size_t)(K * 2) + cb;
    if (j < 2) srcB[j] = (const char*)BT + (size_t)(n0 + R) * (size_t)(K * 2) + cb;
  }

  const int NT = K >> 6;
  for (int t = 0; t < NT; ++t) {
    __syncthreads();
#pragma unroll
    for (int j = 0; j < 4; j++)
      gl_lds16(srcA[j] + (size_t)t * 128, As + j * 4096 + tid * 16);
#pragma unroll
    for (int j = 0; j < 2; j++)
      gl_lds16(srcB[j] + (size_t)t * 128, Bs + j * 4096 + tid * 16);
    __syncthreads();
    bf16x8 af[4][2], bfr[2][2];
#pragma unroll
    for (int mf = 0; mf < 4; mf++)
#pragma unroll
      for (int ks = 0; ks < 2; ks++) {
        const int R = wm + mf * 16 + l15;
        af[mf][ks] = *(const bf16x8*)(As + (R << 7) + ((ks * 64 + lg * 16) ^ ((R & 7) << 4)));
      }
#pragma unroll
    for (int nf = 0; nf < 2; nf++)
#pragma unroll
      for (int ks = 0; ks < 2; ks++) {
        const int R = wn + nf * 16 + l15;
        bfr[nf][ks] = *(const bf16x8*)(Bs + (R << 7) + ((ks * 64 + lg * 16) ^ ((R & 7) << 4)));
      }
#pragma unroll
    for (int mf = 0; mf < 4; mf++)
#pragma unroll
      for (int nf = 0; nf < 2; nf++)
#pragma unroll
        for (int ks = 0; ks < 2; ks++)
          acc[mf][nf] = __builtin_amdgcn_mfma_f32_16x16x32_bf16(
              af[mf][ks], bfr[nf][ks], acc[mf][nf], 0, 0, 0);
  }

  if (OUT_BF16) {
    __syncthreads();
    unsigned short (*Ct)[64] = (unsigned short(*)[64])As;
#pragma unroll
    for (int nf = 0; nf < 2; nf++) {
      const int col = wn + nf * 16 + l15;
      const float bv = bias ? bias[n0 + col] : 0.0f;
#pragma unroll
      for (int mf = 0; mf < 4; mf++) {
        const int rbase = wm + mf * 16 + lg * 4;
#pragma unroll
        for (int r = 0; r < 4; r++) {
          float v = acc[mf][nf][r] + bv;
          if (ACT == 2) v = 0.5f * v * (1.0f + erff(v * 0.70710678118654752f));
          Ct[rbase + r][col] = f2bf(v);
        }
      }
    }
    __syncthreads();
    unsigned short* Cb = (unsigned short*)Cout;
#pragma unroll
    for (int pass = 0; pass < 4; pass++) {
      const int idx = pass * 256 + tid;
      const int row = idx >> 3, c8 = (idx & 7) * 8;
      const uint4 d = *(const uint4*)&Ct[row][c8];
      *(uint4*)(Cb + (size_t)(m0 + row) * ldc + n0 + c8) = d;
    }
  } else {
#pragma unroll
    for (int nf = 0; nf < 2; nf++) {
      const int col = n0 + wn + nf * 16 + l15;
      const float bv = bias ? bias[col] : 0.0f;
#pragma unroll
      for (int mf = 0; mf < 4; mf++) {
        const int rbase = m0 + wm + mf * 16 + lg * 4;
#pragma unroll
        for (int r = 0; r < 4; r++) {
          float v = acc[mf][nf][r] + bv;
          if (ACT == 2) v = 0.5f * v * (1.0f + erff(v * 0.70710678118654752f));
          const size_t idx = (size_t)(rbase + r) * ldc + col;
          if (RESID) v += resid[idx];
          ((float*)Cout)[idx] = v;
        }
      }
    }
  }
}

// ---------------------------------------------------------------------------
// gemm_dual (r13-verified): wo (K=1024) + Cw (K=128) in one 1024-block launch
// ---------------------------------------------------------------------------
__global__ __launch_bounds__(256, 4) void gemm_dual(
    const unsigned short* __restrict__ A1, const unsigned short* __restrict__ BT1,
    const float* __restrict__ bias1, unsigned short* __restrict__ C1, int K1,
    const unsigned short* __restrict__ A2, const unsigned short* __restrict__ BT2,
    const float* __restrict__ bias2, unsigned short* __restrict__ C2, int K2)
{
  __shared__ char As[16384];
  __shared__ char Bs[8192];
  const int nwg = gridDim.x;
  int bid = blockIdx.x;
  {
    const int q = nwg >> 3, r = nwg & 7, xx = bid & 7, o = bid >> 3;
    bid = (xx < r ? xx * (q + 1) : r * (q + 1) + (xx - r) * q) + o;
  }
  const int job = bid >> 9;
  const int inner = bid & 511;
  const unsigned short* A  = job ? A2 : A1;
  const unsigned short* BT = job ? BT2 : BT1;
  const float* bias        = job ? bias2 : bias1;
  unsigned short* C        = job ? C2 : C1;
  const int K              = job ? K2 : K1;
  const int m0 = (inner & 31) * 128;
  const int n0 = (inner >> 5) * 64;
  const int ldc = 1024;

  const int tid = threadIdx.x, lane = tid & 63, wave = tid >> 6;
  const int l15 = lane & 15, lg = lane >> 4;
  const int wm = (wave & 1) * 64, wn = (wave >> 1) * 32;
  f32x4 acc[4][2];
#pragma unroll
  for (int i = 0; i < 4; i++)
#pragma unroll
    for (int j = 0; j < 2; j++) acc[i][j] = (f32x4){0.f, 0.f, 0.f, 0.f};

  const char* srcA[4]; const char* srcB[2];
#pragma unroll
  for (int j = 0; j < 4; j++) {
    const int p = j * 4096 + tid * 16;
    const int R = p >> 7;
    const int cb = (p & 127) ^ ((R & 7) << 4);
    srcA[j] = (const char*)A + (size_t)(m0 + R) * (size_t)(K * 2) + cb;
    if (j < 2) srcB[j] = (const char*)BT + (size_t)(n0 + R) * (size_t)(K * 2) + cb;
  }

  const int NT = K >> 6;
  for (int t = 0; t < NT; ++t) {
    __syncthreads();
#pragma unroll
    for (int j = 0; j < 4; j++)
      gl_lds16(srcA[j] + (size_t)t * 128, As + j * 4096 + tid * 16);
#pragma unroll
    for (int j = 0; j < 2; j++)
      gl_lds16(srcB[j] + (size_t)t * 128, Bs + j * 4096 + tid * 16);
    __syncthreads();
    bf16x8 af[4][2], bfr[2][2];
#pragma unroll
    for (int mf = 0; mf < 4; mf++)
#pragma unroll
      for (int ks = 0; ks < 2; ks++) {
        const int R = wm + mf * 16 + l15;
        af[mf][ks] = *(const bf16x8*)(As + (R << 7) + ((ks * 64 + lg * 16) ^ ((R & 7) << 4)));
      }
#pragma unroll
    for (int nf = 0; nf < 2; nf++)
#pragma unroll
      for (int ks = 0; ks < 2; ks++) {
        const int R = wn + nf * 16 + l15;
        bfr[nf][ks] = *(const bf16x8*)(Bs + (R << 7) + ((ks * 64 + lg * 16) ^ ((R & 7) << 4)));
      }
#pragma unroll
    for (int mf = 0; mf < 4; mf++)
#pragma unroll
      for (int nf = 0; nf < 2; nf++)
#pragma unroll
        for (int ks = 0; ks < 2; ks++)
          acc[mf][nf] = __builtin_amdgcn_mfma_f32_16x16x32_bf16(
              af[mf][ks], bfr[nf][ks], acc[mf][nf], 0, 0, 0);
  }

  __syncthreads();
  unsigned short (*Ct)[64] = (unsigned short(*)[64])As;
#pragma unroll
  for (int nf = 0; nf < 2; nf++) {
    const int col = wn + nf * 16 + l15;
    const float bv = bias ? bias[n0 + col] : 0.0f;
#pragma unroll
    for (int mf = 0; mf < 4; mf++) {
      const int rbase = wm + mf * 16 + lg * 4;
#pragma unroll
      for (int r = 0; r < 4; r++)
        Ct[rbase + r][col] = f2bf(acc[mf][nf][r] + bv);
    }
  }
  __syncthreads();
#pragma unroll
  for (int pass = 0; pass < 4; pass++) {
    const int idx = pass * 256 + tid;
    const int row = idx >> 3, c8 = (idx & 7) * 8;
    const uint4 d = *(const uint4*)&Ct[row][c8];
    *(uint4*)(C + (size_t)(m0 + row) * ldc + n0 + c8) = d;
  }
}

// ---------------------------------------------------------------------------
// Attention (QBLK=32) reading HEAD-CONTIGUOUS Qp/Kp (128B rows) + VT;
// front-piggybacked SSM scan (x=0,1).
// ---------------------------------------------------------------------------
__global__ __launch_bounds__(256, 4) void attn_scan_kernel(
    const unsigned short* __restrict__ qkvgu, const unsigned short* __restrict__ Qp,
    const unsigned short* __restrict__ Kp, const unsigned short* __restrict__ VT,
    unsigned short* __restrict__ ao, const float* __restrict__ Avec,
    const float* __restrict__ s0, unsigned short* __restrict__ states,
    float* __restrict__ out_state)
{
  __shared__ float S[32][308];
  const int tid = threadIdx.x;

  if (blockIdx.x < 2) {
    // ---- SSM scan: block per batch, 4 chunks of 512, 2 states/lane ----
    if (blockIdx.y != 0 || blockIdx.z != 0) return;
    float (*finals)[128] = (float(*)[128])&S[0][0];
    const int b = blockIdx.x;
    const int c = tid >> 6;
    const int n0 = (tid & 63) * 2;
    const float a0 = Avec[n0], a1 = Avec[n0 + 1];
    float sv0 = (c == 0) ? s0[b * 128 + n0]     : 0.0f;
    float sv1 = (c == 0) ? s0[b * 128 + n0 + 1] : 0.0f;
    const size_t ubase = (size_t)b * T_LEN * LDQ + 4096 + n0;
    unsigned short* sp = states + (size_t)b * T_LEN * N_STATE + n0;
    const int t0 = c * 512;
#pragma unroll 8
    for (int t = t0; t < t0 + 512; t++) {
      const ushort2 u = *(const ushort2*)&qkvgu[ubase + (size_t)t * LDQ];
      sv0 = fmaf(a0, sv0, bf2f(u.x));
      sv1 = fmaf(a1, sv1, bf2f(u.y));
      ushort2 o; o.x = f2bf(sv0); o.y = f2bf(sv1);
      *(ushort2*)&sp[(size_t)t * N_STATE] = o;
    }
    finals[c][n0] = sv0;
    finals[c][n0 + 1] = sv1;
    if (c == 3) { out_state[b * 128 + n0] = sv0; out_state[b * 128 + n0 + 1] = sv1; }
    __syncthreads();
    if (c > 0) {
      const float c0 = finals[c - 1][n0];
      const float c1 = finals[c - 1][n0 + 1];
      float f0 = a0, f1 = a1;
      for (int t = t0; t < t0 + 512; t++) {
        if (f0 == 0.0f && f1 == 0.0f) break;
        ushort2 cur = *(ushort2*)&sp[(size_t)t * N_STATE];
        cur.x = f2bf(bf2f(cur.x) + f0 * c0);
        cur.y = f2bf(bf2f(cur.y) + f1 * c1);
        *(ushort2*)&sp[(size_t)t * N_STATE] = cur;
        f0 *= a0; f1 *= a1;
      }
    }
    return;
  }

  unsigned short* P = (unsigned short*)&S[0][0];   // row stride 616 ushorts
  const int xb = blockIdx.x - 2;
  const int bx = ((xb & 7) << 3) | (xb >> 3);      // XCD chunk (64 entries)
  const int q0 = bx * 32;
  const int h  = blockIdx.y;
  const int b  = blockIdx.z;
  const int bh = b * 16 + h;
  const int lane = tid & 63, wave = tid >> 6;
  const int l15 = lane & 15, lg = lane >> 4;
  const int qt = wave & 1;
  const int kstart = q0 - 256;
  const size_t hbase = (size_t)bh * T_LEN;

  // ---- QK^T: wave (qt, parity); 9 unrolled trips; Kp rows 128B apart ----
  {
    const unsigned short* qp = Qp + (hbase + q0 + qt * 16 + l15) * 64 + lg * 8;
    const bf16x8 aq0 = *(const bf16x8*)qp;
    const bf16x8 aq1 = *(const bf16x8*)(qp + 32);
    const int kp0 = wave >> 1;
#pragma unroll
    for (int i = 0; i < 9; i++) {
      const int kt = kp0 + 2 * i;
      const int kbase = kstart + kt * 16;
      const int krow = kbase + l15;
      const int krc = krow < 0 ? 0 : krow;
      const unsigned short* kp = Kp + (hbase + krc) * 64 + lg * 8;
      const bf16x8 bk0 = *(const bf16x8*)kp;
      const bf16x8 bk1 = *(const bf16x8*)(kp + 32);
      f32x4 sacc = (f32x4){0.f, 0.f, 0.f, 0.f};
      sacc = __builtin_amdgcn_mfma_f32_16x16x32_bf16(aq0, bk0, sacc, 0, 0, 0);
      sacc = __builtin_amdgcn_mfma_f32_16x16x32_bf16(aq1, bk1, sacc, 0, 0, 0);
#pragma unroll
      for (int r = 0; r < 4; r++) {
        const int qi = q0 + qt * 16 + lg * 4 + r;
        const int kj = kbase + l15;
        const bool ok = (kj >= 0) && (kj <= qi) && (qi - kj < WINDOW);
        S[qt * 16 + lg * 4 + r][kt * 16 + l15] = ok ? sacc[r] * 0.125f : -1e30f;
      }
    }
  }
  __syncthreads();

  // ---- softmax: 8 lanes/row; exp stored back to S; P bf16 aliased ----
  {
    const int row = tid >> 3, sub = tid & 7;
    float mx = -1e30f;
    for (int c = sub; c < 288; c += 8) mx = fmaxf(mx, S[row][c]);
#pragma unroll
    for (int off = 4; off >= 1; off >>= 1) mx = fmaxf(mx, __shfl_xor(mx, off));
    float sum = 0.f;
    for (int c = sub; c < 288; c += 8) {
      const float e = __expf(S[row][c] - mx);
      S[row][c] = e;
      sum += e;
    }
#pragma unroll
    for (int off = 4; off >= 1; off >>= 1) sum += __shfl_xor(sum, off);
    const float inv = 1.0f / sum;
    unsigned short* Prow = P + row * 616;
    for (int c = sub; c < 288; c += 8)
      Prow[c] = f2bf(S[row][c] * inv);
  }
  __syncthreads();

  // ---- PV: wave (qt, d-pair); VT b128 reads, 9 k-steps ----
  {
    const int dt0 = (wave >> 1) * 2;
#pragma unroll
    for (int j = 0; j < 2; j++) {
      const int dn = (dt0 + j) * 16 + l15;
      const unsigned short* vrow = VT + (hbase * 64 / T_LEN * T_LEN) + ((size_t)bh * 64 + dn) * T_LEN - (size_t)bh * 64 * T_LEN + ((size_t)bh * 64 + dn) * 0;
      // simplified correct base:
      vrow = VT + ((size_t)bh * 64 + dn) * T_LEN;
      f32x4 oacc = (f32x4){0.f, 0.f, 0.f, 0.f};
#pragma unroll
      for (int ks = 0; ks < 9; ks++) {
        const bf16x8 pa = *(const bf16x8*)(P + (qt * 16 + l15) * 616 + ks * 32 + lg * 8);
        int t = kstart + ks * 32 + lg * 8;
        t = t < 0 ? 0 : (t > T_LEN - 8 ? T_LEN - 8 : t);
        const bf16x8 vb = *(const bf16x8*)(vrow + t);
        oacc = __builtin_amdgcn_mfma_f32_16x16x32_bf16(pa, vb, oacc, 0, 0, 0);
      }
#pragma unroll
      for (int r = 0; r < 4; r++)
        ao[((size_t)b * T_LEN + q0 + qt * 16 + lg * 4 + r) * D_MODEL + h * 64 + dn] = f2bf(oacc[r]);
    }
  }
}

// ---------------------------------------------------------------------------
// Fused gate + residual + LayerNorm2: one block per row.
// ---------------------------------------------------------------------------
__global__ __launch_bounds__(256) void fusion_ln2_kernel(
    const float* __restrict__ x, const unsigned short* __restrict__ qkvgu,
    const unsigned short* __restrict__ attn, const unsigned short* __restrict__ ssm,
    const float* __restrict__ g2, const float* __restrict__ b2,
    float* __restrict__ out, unsigned short* __restrict__ xn2)
{
  const int row = blockIdx.x, tid = threadIdx.x;
  const size_t e4 = (size_t)row * 1024 + tid * 4;
  const float4 xv = *(const float4*)(x + e4);
  const ushort4 au = *(const ushort4*)(attn + e4);
  const ushort4 su = *(const ushort4*)(ssm + e4);
  const ushort4 gu = *(const ushort4*)(qkvgu + (size_t)row * LDQ + 3072 + tid * 4);
  float4 o;
  {
    const float ga = 1.0f / (1.0f + __expf(-bf2f(gu.x)));
    const float gb = 1.0f / (1.0f + __expf(-bf2f(gu.y)));
    const float gc = 1.0f / (1.0f + __expf(-bf2f(gu.z)));
    const float gd = 1.0f / (1.0f + __expf(-bf2f(gu.w)));
    o.x = xv.x + ga * bf2f(au.x) + (1.0f - ga) * bf2f(su.x);
    o.y = xv.y + gb * bf2f(au.y) + (1.0f - gb) * bf2f(su.y);
    o.z = xv.z + gc * bf2f(au.z) + (1.0f - gc) * bf2f(su.z);
    o.w = xv.w + gd * bf2f(au.w) + (1.0f - gd) * bf2f(su.w);
  }
  *(float4*)(out + e4) = o;

  float s  = o.x + o.y + o.z + o.w;
  float s2 = o.x * o.x + o.y * o.y + o.z * o.z + o.w * o.w;
#pragma unroll
  for (int off = 32; off >= 1; off >>= 1) {
    s  += __shfl_down(s, off);
    s2 += __shfl_down(s2, off);
  }
  __shared__ float red[8];
  const int wave = tid >> 6;
  if ((tid & 63) == 0) { red[wave] = s; red[4 + wave] = s2; }
  __syncthreads();
  s  = red[0] + red[1] + red[2] + red[3];
  s2 = red[4] + red[5] + red[6] + red[7];
  const float mu = s * (1.0f / 1024.0f);
  const float rs = rsqrtf(s2 * (1.0f / 1024.0f) - mu * mu + 1e-5f);
  const float4 gv = ((const float4*)g2)[tid];
  const float4 bv = ((const float4*)b2)[tid];
  ushort4 ov;
  ov.x = f2bf((o.x - mu) * rs * gv.x + bv.x);
  ov.y = f2bf((o.y - mu) * rs * gv.y + bv.y);
  ov.z = f2bf((o.z - mu) * rs * gv.z + bv.z);
  ov.w = f2bf((o.w - mu) * rs * gv.w + bv.w);
  ((ushort4*)(xn2 + (size_t)row * 1024))[tid] = ov;
}

// ---------------------------------------------------------------------------
extern "C" void kernel_launch(void* const* d_in, const int* in_sizes, int n_in,
                              void* d_out, int out_size, void* d_ws, size_t ws_size,
                              hipStream_t stream)
{
  const float* x     = (const float*)d_in[0];
  const float* ssm0  = (const float*)d_in[1];
  const float* ln1_g = (const float*)d_in[2];
  const float* ln1_b = (const float*)d_in[3];
  const float* wq    = (const float*)d_in[4];
  const float* bq    = (const float*)d_in[5];
  const float* wk    = (const float*)d_in[6];
  const float* bk    = (const float*)d_in[7];
  const float* wv    = (const float*)d_in[8];
  const float* bv    = (const float*)d_in[9];
  const float* wo    = (const float*)d_in[10];
  const float* bo    = (const float*)d_in[11];
  const float* wg    = (const float*)d_in[12];
  const float* bg    = (const float*)d_in[13];
  const float* Av    = (const float*)d_in[14];
  const float* Bw    = (const float*)d_in[15];
  const float* Cw    = (const float*)d_in[16];
  const float* ln2_g = (const float*)d_in[17];
  const float* ln2_b = (const float*)d_in[18];
  const float* w1    = (const float*)d_in[19];
  const float* b1    = (const float*)d_in[20];
  const float* w2    = (const float*)d_in[21];
  const float* b2    = (const float*)d_in[22];

  char* p = (char*)d_ws;
  auto take = [&](size_t bytes) { char* q = p; p += (bytes + 255) & ~(size_t)255; return q; };
  unsigned short* WcatT  = (unsigned short*)take((size_t)LDQ * 1024 * 2);
  unsigned short* woT    = (unsigned short*)take((size_t)1024 * 1024 * 2);
  unsigned short* CwT    = (unsigned short*)take((size_t)1024 * 128 * 2);
  unsigned short* w1T    = (unsigned short*)take((size_t)4096 * 1024 * 2);
  unsigned short* w2T    = (unsigned short*)take((size_t)1024 * 4096 * 2);
  float*          bcat   = (float*)take((size_t)LDQ * 4);
  unsigned short* xn     = (unsigned short*)take((size_t)M_ROWS * 1024 * 2);
  unsigned short* qkvgu  = (unsigned short*)take((size_t)M_ROWS * LDQ * 2);
  unsigned short* VT     = (unsigned short*)take((size_t)BATCH * N_HEADS * 64 * T_LEN * 2);
  unsigned short* ao     = (unsigned short*)take((size_t)M_ROWS * 1024 * 2);
  unsigned short* states = (unsigned short*)take((size_t)M_ROWS * N_STATE * 2);
  unsigned short* attn_o = (unsigned short*)take((size_t)M_ROWS * 1024 * 2);
  unsigned short* ssm_o  = (unsigned short*)take((size_t)M_ROWS * 1024 * 2);
  unsigned short* hbuf   = qkvgu;   // alias: qkvgu dead after fusion
  unsigned short* Qp     = attn_o;  // alias: attn_o written only after attention
  unsigned short* Kp     = ssm_o;   // alias: ssm_o  written only after attention

  float* outx = (float*)d_out;
  float* out_state = outx + (size_t)M_ROWS * 1024;

  // --- weight prep (single launch) ---
  prep_kernel<<<13585, 256, 0, stream>>>(
      wq, wk, wv, wg, wo, Bw, Cw, w1, w2, bq, bk, bv, bg,
      WcatT, woT, CwT, w1T, w2T, bcat);

  // --- forward ---
  ln_kernel<<<M_ROWS, 256, 0, stream>>>(x, ln1_g, ln1_b, xn);
  gemm128ho<0><<<32 * 34, 256, 0, stream>>>(xn, WcatT, bcat, qkvgu, LDQ, 1024, 34);
  qkvpack_kernel<<<dim3(64, 3, 32), 256, 0, stream>>>(qkvgu, Qp, Kp, VT);
  attn_scan_kernel<<<dim3(66, 16, 2), 256, 0, stream>>>(
      qkvgu, Qp, Kp, VT, ao, Av, ssm0, states, out_state);
  gemm_dual<<<1024, 256, 0, stream>>>(
      ao, woT, bo, attn_o, 1024,
      states, CwT, nullptr, ssm_o, 128);
  fusion_ln2_kernel<<<4096, 256, 0, stream>>>(
      x, qkvgu, attn_o, ssm_o, ln2_g, ln2_b, outx, xn);
  gemm128ho<2><<<32 * 32, 256, 0, stream>>>(xn, w1T, b1, hbuf, 4096, 1024, 32);
  gemm_ho<0, false, true><<<32 * 16, 256, 0, stream>>>(
      hbuf, w2T, b2, outx, outx, 1024, 4096, 32);
}

// Round 18
// 291.745 us; speedup vs baseline: 1.0268x; 1.0268x over previous
//
#include <hip/hip_runtime.h>

typedef __attribute__((ext_vector_type(8))) short bf16x8;
typedef __attribute__((ext_vector_type(4))) float f32x4;

#define D_MODEL 1024
#define T_LEN 2048
#define BATCH 2
#define N_HEADS 16
#define D_HEAD 64
#define WINDOW 256
#define N_STATE 128
#define D_FF 4096
#define N_CAT 4224   // 4*D_MODEL + N_STATE
#define LDQ 4352     // N_CAT padded
#define M_ROWS 4096  // B*T

static __device__ __forceinline__ float bf2f(unsigned short u) {
  union { unsigned int i; float f; } v; v.i = ((unsigned int)u) << 16; return v.f;
}
static __device__ __forceinline__ unsigned short f2bf(float f) {
  unsigned int x = __float_as_uint(f);
  return (unsigned short)((x + 0x7FFFu + ((x >> 16) & 1u)) >> 16);
}

static __device__ __forceinline__ void gl_lds16(const void* g, void* l) {
  __builtin_amdgcn_global_load_lds(
      (const __attribute__((address_space(1))) unsigned int*)g,
      (__attribute__((address_space(3))) unsigned int*)l, 16, 0, 0);
}

// ---------------------------------------------------------------------------
// prep_kernel: weight transposes (f32->bf16) + bias concat + LN1, ONE launch.
//   [0,5120)       wq/wk/wv/wg -> WcatT, wo -> woT
//   [5120,5248)    Bw -> WcatT rows 4096..4223
//   [5248,5376)    Cw -> CwT
//   [5376,9472)    w1 -> w1T
//   [9472,13568)   w2 -> w2T
//   [13568,13585)  bcat fill
//   [13585,17681)  LN1 row (x -> xn bf16)
// ---------------------------------------------------------------------------
__global__ __launch_bounds__(256) void prep_kernel(
    const float* __restrict__ wq, const float* __restrict__ wk,
    const float* __restrict__ wv, const float* __restrict__ wg,
    const float* __restrict__ wo, const float* __restrict__ Bw,
    const float* __restrict__ Cw, const float* __restrict__ w1,
    const float* __restrict__ w2,
    const float* __restrict__ bq, const float* __restrict__ bk,
    const float* __restrict__ bv, const float* __restrict__ bg,
    const float* __restrict__ x, const float* __restrict__ ln1_g,
    const float* __restrict__ ln1_b,
    unsigned short* __restrict__ WcatT, unsigned short* __restrict__ woT,
    unsigned short* __restrict__ CwT, unsigned short* __restrict__ w1T,
    unsigned short* __restrict__ w2T, float* __restrict__ bcat,
    unsigned short* __restrict__ xn)
{
  __shared__ float tile[32][33];
  __shared__ float red[8];
  const int bid = blockIdx.x;
  const int tid = threadIdx.x;

  if (bid >= 13585) {                      // ---- LN1 ----
    const int row = bid - 13585;
    const float4 xv = ((const float4*)(x + (size_t)row * 1024))[tid];
    float s  = xv.x + xv.y + xv.z + xv.w;
    float s2 = xv.x * xv.x + xv.y * xv.y + xv.z * xv.z + xv.w * xv.w;
#pragma unroll
    for (int off = 32; off >= 1; off >>= 1) {
      s  += __shfl_down(s, off);
      s2 += __shfl_down(s2, off);
    }
    const int wave = tid >> 6;
    if ((tid & 63) == 0) { red[wave] = s; red[4 + wave] = s2; }
    __syncthreads();
    s  = red[0] + red[1] + red[2] + red[3];
    s2 = red[4] + red[5] + red[6] + red[7];
    const float mu = s * (1.0f / 1024.0f);
    const float rs = rsqrtf(s2 * (1.0f / 1024.0f) - mu * mu + 1e-5f);
    const float4 gv = ((const float4*)ln1_g)[tid];
    const float4 bv = ((const float4*)ln1_b)[tid];
    ushort4 o;
    o.x = f2bf((xv.x - mu) * rs * gv.x + bv.x);
    o.y = f2bf((xv.y - mu) * rs * gv.y + bv.y);
    o.z = f2bf((xv.z - mu) * rs * gv.z + bv.z);
    o.w = f2bf((xv.w - mu) * rs * gv.w + bv.w);
    ((ushort4*)(xn + (size_t)row * 1024))[tid] = o;
    return;
  }
  if (bid >= 13568) {                      // ---- bcat ----
    const int i = (bid - 13568) * 256 + tid;
    if (i < LDQ) {
      float v = 0.0f;
      if (i < 1024)      v = bq[i];
      else if (i < 2048) v = bk[i - 1024];
      else if (i < 3072) v = bv[i - 2048];
      else if (i < 4096) v = bg[i - 3072];
      bcat[i] = v;
    }
    return;
  }
  const float* src; unsigned short* dst;
  int N, n_off, ldd, xx, yy;
  if (bid < 5120) {
    const int z = bid >> 10, t = bid & 1023;
    xx = t & 31; yy = t >> 5;
    src = (z == 0) ? wq : (z == 1) ? wk : (z == 2) ? wv : (z == 3) ? wg : wo;
    dst = (z < 4) ? WcatT : woT;
    n_off = (z < 4) ? z * 1024 : 0;
    N = 1024; ldd = 1024;
  } else if (bid < 5248) {
    const int t = bid - 5120; xx = t & 31; yy = t >> 5;
    src = Bw; dst = WcatT; n_off = 4096; N = 128; ldd = 1024;
  } else if (bid < 5376) {
    const int t = bid - 5248; xx = t & 3; yy = t >> 2;
    src = Cw; dst = CwT; n_off = 0; N = 1024; ldd = 128;
  } else if (bid < 9472) {
    const int t = bid - 5376; xx = t & 31; yy = t >> 5;
    src = w1; dst = w1T; n_off = 0; N = 4096; ldd = 1024;
  } else {
    const int t = bid - 9472; xx = t & 127; yy = t >> 7;
    src = w2; dst = w2T; n_off = 0; N = 1024; ldd = 4096;
  }
  const int kt = xx * 32, nt = yy * 32;
  const int c = tid & 31, r0 = tid >> 5;
#pragma unroll
  for (int i = 0; i < 4; i++) {
    const int r = r0 + i * 8;
    tile[r][c] = src[(size_t)(kt + r) * N + nt + c];
  }
  __syncthreads();
#pragma unroll
  for (int i = 0; i < 4; i++) {
    const int r = r0 + i * 8;
    dst[(size_t)(n_off + nt + r) * ldd + kt + c] = f2bf(tile[c][r]);
  }
}

// ---------------------------------------------------------------------------
// gemm128ho: 128x128, BK=64, 4 blocks/CU, GROUP_M=8 + XCD swizzle, LDS-staged
// bf16 epilogue. VOUT: blocks whose n-range overlaps V (cols 2048..3071 of
// qkvgu) also emit the transposed V-slice to VT from the LDS C-tile
// (t = row index -> 16B-contiguous VT writes). Eliminates vtrans kernel.
// ---------------------------------------------------------------------------
template<int ACT, bool VOUT>
__global__ __launch_bounds__(256, 4) void gemm128ho(
    const unsigned short* __restrict__ A, const unsigned short* __restrict__ BT,
    const float* __restrict__ bias, unsigned short* __restrict__ C,
    unsigned short* __restrict__ VT, int ldc, int K, int nby)
{
  __shared__ char smem[32768];
  char* const As = smem;
  char* const Bs = smem + 16384;
  const int nwg = gridDim.x;
  int bid = blockIdx.x;
  {
    const int q = nwg >> 3, r = nwg & 7, xx = bid & 7, o = bid >> 3;
    bid = (xx < r ? xx * (q + 1) : r * (q + 1) + (xx - r) * q) + o;
  }
  const int per_group = 8 * nby;
  const int grp = bid / per_group, rem = bid % per_group;
  const int m0 = (grp * 8 + (rem & 7)) * 128;
  const int n0 = (rem >> 3) * 128;

  const int tid = threadIdx.x, lane = tid & 63, wave = tid >> 6;
  const int l15 = lane & 15, lg = lane >> 4;
  const int wm = (wave >> 1) * 64, wn = (wave & 1) * 64;
  f32x4 acc[4][4];
#pragma unroll
  for (int i = 0; i < 4; i++)
#pragma unroll
    for (int j = 0; j < 4; j++) acc[i][j] = (f32x4){0.f, 0.f, 0.f, 0.f};

  const char* srcA[4]; const char* srcB[4];
#pragma unroll
  for (int j = 0; j < 4; j++) {
    const int p = j * 4096 + tid * 16;
    const int R = p >> 7;
    const int cb = (p & 127) ^ ((R & 7) << 4);
    srcA[j] = (const char*)A  + (size_t)(m0 + R) * (size_t)(K * 2) + cb;
    srcB[j] = (const char*)BT + (size_t)(n0 + R) * (size_t)(K * 2) + cb;
  }

  const int NT = K >> 6;
  for (int t = 0; t < NT; ++t) {
    __syncthreads();
#pragma unroll
    for (int j = 0; j < 4; j++) {
      gl_lds16(srcA[j] + (size_t)t * 128, As + j * 4096 + tid * 16);
      gl_lds16(srcB[j] + (size_t)t * 128, Bs + j * 4096 + tid * 16);
    }
    __syncthreads();
    bf16x8 af[4][2], bfr[4][2];
#pragma unroll
    for (int mf = 0; mf < 4; mf++)
#pragma unroll
      for (int ks = 0; ks < 2; ks++) {
        const int R = wm + mf * 16 + l15;
        af[mf][ks] = *(const bf16x8*)(As + (R << 7) + ((ks * 64 + lg * 16) ^ ((R & 7) << 4)));
      }
#pragma unroll
    for (int nf = 0; nf < 4; nf++)
#pragma unroll
      for (int ks = 0; ks < 2; ks++) {
        const int R = wn + nf * 16 + l15;
        bfr[nf][ks] = *(const bf16x8*)(Bs + (R << 7) + ((ks * 64 + lg * 16) ^ ((R & 7) << 4)));
      }
#pragma unroll
    for (int mf = 0; mf < 4; mf++)
#pragma unroll
      for (int nf = 0; nf < 4; nf++)
#pragma unroll
        for (int ks = 0; ks < 2; ks++)
          acc[mf][nf] = __builtin_amdgcn_mfma_f32_16x16x32_bf16(
              af[mf][ks], bfr[nf][ks], acc[mf][nf], 0, 0, 0);
  }

  __syncthreads();
  unsigned short (*Ct)[128] = (unsigned short(*)[128])smem;
#pragma unroll
  for (int nf = 0; nf < 4; nf++) {
    const int col = wn + nf * 16 + l15;
    const float bv = bias[n0 + col];
#pragma unroll
    for (int mf = 0; mf < 4; mf++) {
      const int rbase = wm + mf * 16 + lg * 4;
#pragma unroll
      for (int r = 0; r < 4; r++) {
        float v = acc[mf][nf][r] + bv;
        if (ACT == 2) v = 0.5f * v * (1.0f + erff(v * 0.70710678118654752f));
        Ct[rbase + r][col] = f2bf(v);
      }
    }
  }
  __syncthreads();
#pragma unroll
  for (int pass = 0; pass < 8; pass++) {
    const int idx = pass * 256 + tid;
    const int row = idx >> 4, c8 = (idx & 15) * 8;
    const uint4 d = *(const uint4*)&Ct[row][c8];
    *(uint4*)(C + (size_t)(m0 + row) * ldc + n0 + c8) = d;
  }

  if (VOUT) {
    const int col = tid >> 1;          // 0..127
    const int nn = n0 + col;
    if (nn >= 2048 && nn < 3072) {
      const int hh = (nn - 2048) >> 6, dd = (nn - 2048) & 63;
      const int bb = m0 >> 11;                 // T_LEN = 2048
      const int rl0 = (tid & 1) * 64;          // local row base (t offset)
      unsigned short* vp = VT + ((size_t)(bb * 16 + hh) * 64 + dd) * T_LEN
                              + (m0 & 2047) + rl0;
#pragma unroll
      for (int s = 0; s < 8; s++) {
        const int rl = rl0 + s * 8;
        ushort4 lo, hi;
        lo.x = Ct[rl + 0][col]; lo.y = Ct[rl + 1][col];
        lo.z = Ct[rl + 2][col]; lo.w = Ct[rl + 3][col];
        hi.x = Ct[rl + 4][col]; hi.y = Ct[rl + 5][col];
        hi.z = Ct[rl + 6][col]; hi.w = Ct[rl + 7][col];
        *(ushort4*)(vp + s * 8)     = lo;
        *(ushort4*)(vp + s * 8 + 4) = hi;
      }
    }
  }
}

// ---------------------------------------------------------------------------
// gemm_ho (r10-verified): 128x64, 4 blocks/CU; bf16-LDS epilogue / f32+resid
// ---------------------------------------------------------------------------
template<int ACT, bool OUT_BF16, bool RESID>
__global__ __launch_bounds__(256, 4) void gemm_ho(
    const unsigned short* __restrict__ A, const unsigned short* __restrict__ BT,
    const float* __restrict__ bias, const float* __restrict__ resid,
    void* __restrict__ Cout, int ldc, int K, int nbx)
{
  __shared__ char As[16384];
  __shared__ char Bs[8192];
  const int nwg = gridDim.x;
  int bid = blockIdx.x;
  {
    const int q = nwg >> 3, r = nwg & 7, xx = bid & 7, o = bid >> 3;
    bid = (xx < r ? xx * (q + 1) : r * (q + 1) + (xx - r) * q) + o;
  }
  const int m0 = (bid % nbx) * 128;
  const int n0 = (bid / nbx) * 64;
  const int tid = threadIdx.x, lane = tid & 63, wave = tid >> 6;
  const int l15 = lane & 15, lg = lane >> 4;
  const int wm = (wave & 1) * 64, wn = (wave >> 1) * 32;
  f32x4 acc[4][2];
#pragma unroll
  for (int i = 0; i < 4; i++)
#pragma unroll
    for (int j = 0; j < 2; j++) acc[i][j] = (f32x4){0.f, 0.f, 0.f, 0.f};

  const char* srcA[4]; const char* srcB[2];
#pragma unroll
  for (int j = 0; j < 4; j++) {
    const int p = j * 4096 + tid * 16;
    const int R = p >> 7;
    const int cb = (p & 127) ^ ((R & 7) << 4);
    srcA[j] = (const char*)A + (size_t)(m0 + R) * (size_t)(K * 2) + cb;
    if (j < 2) srcB[j] = (const char*)BT + (size_t)(n0 + R) * (size_t)(K * 2) + cb;
  }

  const int NT = K >> 6;
  for (int t = 0; t < NT; ++t) {
    __syncthreads();
#pragma unroll
    for (int j = 0; j < 4; j++)
      gl_lds16(srcA[j] + (size_t)t * 128, As + j * 4096 + tid * 16);
#pragma unroll
    for (int j = 0; j < 2; j++)
      gl_lds16(srcB[j] + (size_t)t * 128, Bs + j * 4096 + tid * 16);
    __syncthreads();
    bf16x8 af[4][2], bfr[2][2];
#pragma unroll
    for (int mf = 0; mf < 4; mf++)
#pragma unroll
      for (int ks = 0; ks < 2; ks++) {
        const int R = wm + mf * 16 + l15;
        af[mf][ks] = *(const bf16x8*)(As + (R << 7) + ((ks * 64 + lg * 16) ^ ((R & 7) << 4)));
      }
#pragma unroll
    for (int nf = 0; nf < 2; nf++)
#pragma unroll
      for (int ks = 0; ks < 2; ks++) {
        const int R = wn + nf * 16 + l15;
        bfr[nf][ks] = *(const bf16x8*)(Bs + (R << 7) + ((ks * 64 + lg * 16) ^ ((R & 7) << 4)));
      }
#pragma unroll
    for (int mf = 0; mf < 4; mf++)
#pragma unroll
      for (int nf = 0; nf < 2; nf++)
#pragma unroll
        for (int ks = 0; ks < 2; ks++)
          acc[mf][nf] = __builtin_amdgcn_mfma_f32_16x16x32_bf16(
              af[mf][ks], bfr[nf][ks], acc[mf][nf], 0, 0, 0);
  }

  if (OUT_BF16) {
    __syncthreads();
    unsigned short (*Ct)[64] = (unsigned short(*)[64])As;
#pragma unroll
    for (int nf = 0; nf < 2; nf++) {
      const int col = wn + nf * 16 + l15;
      const float bv = bias ? bias[n0 + col] : 0.0f;
#pragma unroll
      for (int mf = 0; mf < 4; mf++) {
        const int rbase = wm + mf * 16 + lg * 4;
#pragma unroll
        for (int r = 0; r < 4; r++) {
          float v = acc[mf][nf][r] + bv;
          if (ACT == 2) v = 0.5f * v * (1.0f + erff(v * 0.70710678118654752f));
          Ct[rbase + r][col] = f2bf(v);
        }
      }
    }
    __syncthreads();
    unsigned short* Cb = (unsigned short*)Cout;
#pragma unroll
    for (int pass = 0; pass < 4; pass++) {
      const int idx = pass * 256 + tid;
      const int row = idx >> 3, c8 = (idx & 7) * 8;
      const uint4 d = *(const uint4*)&Ct[row][c8];
      *(uint4*)(Cb + (size_t)(m0 + row) * ldc + n0 + c8) = d;
    }
  } else {
#pragma unroll
    for (int nf = 0; nf < 2; nf++) {
      const int col = n0 + wn + nf * 16 + l15;
      const float bv = bias ? bias[col] : 0.0f;
#pragma unroll
      for (int mf = 0; mf < 4; mf++) {
        const int rbase = m0 + wm + mf * 16 + lg * 4;
#pragma unroll
        for (int r = 0; r < 4; r++) {
          float v = acc[mf][nf][r] + bv;
          if (ACT == 2) v = 0.5f * v * (1.0f + erff(v * 0.70710678118654752f));
          const size_t idx = (size_t)(rbase + r) * ldc + col;
          if (RESID) v += resid[idx];
          ((float*)Cout)[idx] = v;
        }
      }
    }
  }
}

// ---------------------------------------------------------------------------
// gemm_dual (r13-verified): wo (K=1024) + Cw (K=128) in one 1024-block launch
// ---------------------------------------------------------------------------
__global__ __launch_bounds__(256, 4) void gemm_dual(
    const unsigned short* __restrict__ A1, const unsigned short* __restrict__ BT1,
    const float* __restrict__ bias1, unsigned short* __restrict__ C1, int K1,
    const unsigned short* __restrict__ A2, const unsigned short* __restrict__ BT2,
    const float* __restrict__ bias2, unsigned short* __restrict__ C2, int K2)
{
  __shared__ char As[16384];
  __shared__ char Bs[8192];
  const int nwg = gridDim.x;
  int bid = blockIdx.x;
  {
    const int q = nwg >> 3, r = nwg & 7, xx = bid & 7, o = bid >> 3;
    bid = (xx < r ? xx * (q + 1) : r * (q + 1) + (xx - r) * q) + o;
  }
  const int job = bid >> 9;
  const int inner = bid & 511;
  const unsigned short* A  = job ? A2 : A1;
  const unsigned short* BT = job ? BT2 : BT1;
  const float* bias        = job ? bias2 : bias1;
  unsigned short* C        = job ? C2 : C1;
  const int K              = job ? K2 : K1;
  const int m0 = (inner & 31) * 128;
  const int n0 = (inner >> 5) * 64;
  const int ldc = 1024;

  const int tid = threadIdx.x, lane = tid & 63, wave = tid >> 6;
  const int l15 = lane & 15, lg = lane >> 4;
  const int wm = (wave & 1) * 64, wn = (wave >> 1) * 32;
  f32x4 acc[4][2];
#pragma unroll
  for (int i = 0; i < 4; i++)
#pragma unroll
    for (int j = 0; j < 2; j++) acc[i][j] = (f32x4){0.f, 0.f, 0.f, 0.f};

  const char* srcA[4]; const char* srcB[2];
#pragma unroll
  for (int j = 0; j < 4; j++) {
    const int p = j * 4096 + tid * 16;
    const int R = p >> 7;
    const int cb = (p & 127) ^ ((R & 7) << 4);
    srcA[j] = (const char*)A + (size_t)(m0 + R) * (size_t)(K * 2) + cb;
    if (j < 2) srcB[j] = (const char*)BT + (size_t)(n0 + R) * (size_t)(K * 2) + cb;
  }

  const int NT = K >> 6;
  for (int t = 0; t < NT; ++t) {
    __syncthreads();
#pragma unroll
    for (int j = 0; j < 4; j++)
      gl_lds16(srcA[j] + (size_t)t * 128, As + j * 4096 + tid * 16);
#pragma unroll
    for (int j = 0; j < 2; j++)
      gl_lds16(srcB[j] + (size_t)t * 128, Bs + j * 4096 + tid * 16);
    __syncthreads();
    bf16x8 af[4][2], bfr[2][2];
#pragma unroll
    for (int mf = 0; mf < 4; mf++)
#pragma unroll
      for (int ks = 0; ks < 2; ks++) {
        const int R = wm + mf * 16 + l15;
        af[mf][ks] = *(const bf16x8*)(As + (R << 7) + ((ks * 64 + lg * 16) ^ ((R & 7) << 4)));
      }
#pragma unroll
    for (int nf = 0; nf < 2; nf++)
#pragma unroll
      for (int ks = 0; ks < 2; ks++) {
        const int R = wn + nf * 16 + l15;
        bfr[nf][ks] = *(const bf16x8*)(Bs + (R << 7) + ((ks * 64 + lg * 16) ^ ((R & 7) << 4)));
      }
#pragma unroll
    for (int mf = 0; mf < 4; mf++)
#pragma unroll
      for (int nf = 0; nf < 2; nf++)
#pragma unroll
        for (int ks = 0; ks < 2; ks++)
          acc[mf][nf] = __builtin_amdgcn_mfma_f32_16x16x32_bf16(
              af[mf][ks], bfr[nf][ks], acc[mf][nf], 0, 0, 0);
  }

  __syncthreads();
  unsigned short (*Ct)[64] = (unsigned short(*)[64])As;
#pragma unroll
  for (int nf = 0; nf < 2; nf++) {
    const int col = wn + nf * 16 + l15;
    const float bv = bias ? bias[n0 + col] : 0.0f;
#pragma unroll
    for (int mf = 0; mf < 4; mf++) {
      const int rbase = wm + mf * 16 + lg * 4;
#pragma unroll
      for (int r = 0; r < 4; r++)
        Ct[rbase + r][col] = f2bf(acc[mf][nf][r] + bv);
    }
  }
  __syncthreads();
#pragma unroll
  for (int pass = 0; pass < 4; pass++) {
    const int idx = pass * 256 + tid;
    const int row = idx >> 3, c8 = (idx & 7) * 8;
    const uint4 d = *(const uint4*)&Ct[row][c8];
    *(uint4*)(C + (size_t)(m0 + row) * ldc + n0 + c8) = d;
  }
}

// ---------------------------------------------------------------------------
// Attention (QBLK=32, r15-verified best) + front-piggybacked SSM scan (x=0,1)
// ---------------------------------------------------------------------------
__global__ __launch_bounds__(256, 4) void attn_scan_kernel(
    const unsigned short* __restrict__ qkvgu, const unsigned short* __restrict__ VT,
    unsigned short* __restrict__ ao, const float* __restrict__ Avec,
    const float* __restrict__ s0, unsigned short* __restrict__ states,
    float* __restrict__ out_state)
{
  __shared__ float S[32][308];
  const int tid = threadIdx.x;

  if (blockIdx.x < 2) {
    if (blockIdx.y != 0 || blockIdx.z != 0) return;
    float (*finals)[128] = (float(*)[128])&S[0][0];
    const int b = blockIdx.x;
    const int c = tid >> 6;
    const int n0 = (tid & 63) * 2;
    const float a0 = Avec[n0], a1 = Avec[n0 + 1];
    float sv0 = (c == 0) ? s0[b * 128 + n0]     : 0.0f;
    float sv1 = (c == 0) ? s0[b * 128 + n0 + 1] : 0.0f;
    const size_t ubase = (size_t)b * T_LEN * LDQ + 4096 + n0;
    unsigned short* sp = states + (size_t)b * T_LEN * N_STATE + n0;
    const int t0 = c * 512;
#pragma unroll 8
    for (int t = t0; t < t0 + 512; t++) {
      const ushort2 u = *(const ushort2*)&qkvgu[ubase + (size_t)t * LDQ];
      sv0 = fmaf(a0, sv0, bf2f(u.x));
      sv1 = fmaf(a1, sv1, bf2f(u.y));
      ushort2 o; o.x = f2bf(sv0); o.y = f2bf(sv1);
      *(ushort2*)&sp[(size_t)t * N_STATE] = o;
    }
    finals[c][n0] = sv0;
    finals[c][n0 + 1] = sv1;
    if (c == 3) { out_state[b * 128 + n0] = sv0; out_state[b * 128 + n0 + 1] = sv1; }
    __syncthreads();
    if (c > 0) {
      const float c0 = finals[c - 1][n0];
      const float c1 = finals[c - 1][n0 + 1];
      float f0 = a0, f1 = a1;
      for (int t = t0; t < t0 + 512; t++) {
        if (f0 == 0.0f && f1 == 0.0f) break;
        ushort2 cur = *(ushort2*)&sp[(size_t)t * N_STATE];
        cur.x = f2bf(bf2f(cur.x) + f0 * c0);
        cur.y = f2bf(bf2f(cur.y) + f1 * c1);
        *(ushort2*)&sp[(size_t)t * N_STATE] = cur;
        f0 *= a0; f1 *= a1;
      }
    }
    return;
  }

  unsigned short* P = (unsigned short*)&S[0][0];   // row stride 616 ushorts
  const int xb = blockIdx.x - 2;
  const int bx = ((xb & 7) << 3) | (xb >> 3);      // XCD chunk (64 entries)
  const int q0 = bx * 32;
  const int h  = blockIdx.y;
  const int b  = blockIdx.z;
  const int lane = tid & 63, wave = tid >> 6;
  const int l15 = lane & 15, lg = lane >> 4;
  const int qt = wave & 1;
  const int kstart = q0 - 256;
  const size_t rowbase = (size_t)b * T_LEN;

  {
    const unsigned short* qp = qkvgu + (rowbase + q0 + qt * 16 + l15) * LDQ + h * 64 + lg * 8;
    const bf16x8 aq0 = *(const bf16x8*)qp;
    const bf16x8 aq1 = *(const bf16x8*)(qp + 32);
    for (int kt = (wave >> 1); kt < 18; kt += 2) {
      const int kbase = kstart + kt * 16;
      const int krow = kbase + l15;
      const int krc = krow < 0 ? 0 : krow;
      const unsigned short* kp = qkvgu + (rowbase + krc) * LDQ + 1024 + h * 64 + lg * 8;
      const bf16x8 bk0 = *(const bf16x8*)kp;
      const bf16x8 bk1 = *(const bf16x8*)(kp + 32);
      f32x4 sacc = (f32x4){0.f, 0.f, 0.f, 0.f};
      sacc = __builtin_amdgcn_mfma_f32_16x16x32_bf16(aq0, bk0, sacc, 0, 0, 0);
      sacc = __builtin_amdgcn_mfma_f32_16x16x32_bf16(aq1, bk1, sacc, 0, 0, 0);
#pragma unroll
      for (int r = 0; r < 4; r++) {
        const int qi = q0 + qt * 16 + lg * 4 + r;
        const int kj = kbase + l15;
        const bool ok = (kj >= 0) && (kj <= qi) && (qi - kj < WINDOW);
        S[qt * 16 + lg * 4 + r][kt * 16 + l15] = ok ? sacc[r] * 0.125f : -1e30f;
      }
    }
  }
  __syncthreads();

  {
    const int row = tid >> 3, sub = tid & 7;
    float mx = -1e30f;
    for (int c = sub; c < 288; c += 8) mx = fmaxf(mx, S[row][c]);
#pragma unroll
    for (int off = 4; off >= 1; off >>= 1) mx = fmaxf(mx, __shfl_xor(mx, off));
    float sum = 0.f;
    for (int c = sub; c < 288; c += 8) sum += __expf(S[row][c] - mx);
#pragma unroll
    for (int off = 4; off >= 1; off >>= 1) sum += __shfl_xor(sum, off);
    const float inv = 1.0f / sum;
    unsigned short* Prow = P + row * 616;
    for (int c = sub; c < 288; c += 8)
      Prow[c] = f2bf(__expf(S[row][c] - mx) * inv);
  }
  __syncthreads();

  {
    const int dt0 = (wave >> 1) * 2;
#pragma unroll
    for (int j = 0; j < 2; j++) {
      const int dn = (dt0 + j) * 16 + l15;
      const unsigned short* vrow = VT + ((size_t)(b * 16 + h) * 64 + dn) * T_LEN;
      f32x4 oacc = (f32x4){0.f, 0.f, 0.f, 0.f};
#pragma unroll
      for (int ks = 0; ks < 9; ks++) {
        const bf16x8 pa = *(const bf16x8*)(P + (qt * 16 + l15) * 616 + ks * 32 + lg * 8);
        int t = kstart + ks * 32 + lg * 8;
        t = t < 0 ? 0 : (t > T_LEN - 8 ? T_LEN - 8 : t);
        const bf16x8 vb = *(const bf16x8*)(vrow + t);
        oacc = __builtin_amdgcn_mfma_f32_16x16x32_bf16(pa, vb, oacc, 0, 0, 0);
      }
#pragma unroll
      for (int r = 0; r < 4; r++)
        ao[(rowbase + q0 + qt * 16 + lg * 4 + r) * D_MODEL + h * 64 + dn] = f2bf(oacc[r]);
    }
  }
}

// ---------------------------------------------------------------------------
// Fused gate + residual + LayerNorm2: one block per row.
// ---------------------------------------------------------------------------
__global__ __launch_bounds__(256) void fusion_ln2_kernel(
    const float* __restrict__ x, const unsigned short* __restrict__ qkvgu,
    const unsigned short* __restrict__ attn, const unsigned short* __restrict__ ssm,
    const float* __restrict__ g2, const float* __restrict__ b2,
    float* __restrict__ out, unsigned short* __restrict__ xn2)
{
  const int row = blockIdx.x, tid = threadIdx.x;
  const size_t e4 = (size_t)row * 1024 + tid * 4;
  const float4 xv = *(const float4*)(x + e4);
  const ushort4 au = *(const ushort4*)(attn + e4);
  const ushort4 su = *(const ushort4*)(ssm + e4);
  const ushort4 gu = *(const ushort4*)(qkvgu + (size_t)row * LDQ + 3072 + tid * 4);
  float4 o;
  {
    const float ga = 1.0f / (1.0f + __expf(-bf2f(gu.x)));
    const float gb = 1.0f / (1.0f + __expf(-bf2f(gu.y)));
    const float gc = 1.0f / (1.0f + __expf(-bf2f(gu.z)));
    const float gd = 1.0f / (1.0f + __expf(-bf2f(gu.w)));
    o.x = xv.x + ga * bf2f(au.x) + (1.0f - ga) * bf2f(su.x);
    o.y = xv.y + gb * bf2f(au.y) + (1.0f - gb) * bf2f(su.y);
    o.z = xv.z + gc * bf2f(au.z) + (1.0f - gc) * bf2f(su.z);
    o.w = xv.w + gd * bf2f(au.w) + (1.0f - gd) * bf2f(su.w);
  }
  *(float4*)(out + e4) = o;

  float s  = o.x + o.y + o.z + o.w;
  float s2 = o.x * o.x + o.y * o.y + o.z * o.z + o.w * o.w;
#pragma unroll
  for (int off = 32; off >= 1; off >>= 1) {
    s  += __shfl_down(s, off);
    s2 += __shfl_down(s2, off);
  }
  __shared__ float red[8];
  const int wave = tid >> 6;
  if ((tid & 63) == 0) { red[wave] = s; red[4 + wave] = s2; }
  __syncthreads();
  s  = red[0] + red[1] + red[2] + red[3];
  s2 = red[4] + red[5] + red[6] + red[7];
  const float mu = s * (1.0f / 1024.0f);
  const float rs = rsqrtf(s2 * (1.0f / 1024.0f) - mu * mu + 1e-5f);
  const float4 gv = ((const float4*)g2)[tid];
  const float4 bv = ((const float4*)b2)[tid];
  ushort4 ov;
  ov.x = f2bf((o.x - mu) * rs * gv.x + bv.x);
  ov.y = f2bf((o.y - mu) * rs * gv.y + bv.y);
  ov.z = f2bf((o.z - mu) * rs * gv.z + bv.z);
  ov.w = f2bf((o.w - mu) * rs * gv.w + bv.w);
  ((ushort4*)(xn2 + (size_t)row * 1024))[tid] = ov;
}

// ---------------------------------------------------------------------------
extern "C" void kernel_launch(void* const* d_in, const int* in_sizes, int n_in,
                              void* d_out, int out_size, void* d_ws, size_t ws_size,
                              hipStream_t stream)
{
  const float* x     = (const float*)d_in[0];
  const float* ssm0  = (const float*)d_in[1];
  const float* ln1_g = (const float*)d_in[2];
  const float* ln1_b = (const float*)d_in[3];
  const float* wq    = (const float*)d_in[4];
  const float* bq    = (const float*)d_in[5];
  const float* wk    = (const float*)d_in[6];
  const float* bk    = (const float*)d_in[7];
  const float* wv    = (const float*)d_in[8];
  const float* bv    = (const float*)d_in[9];
  const float* wo    = (const float*)d_in[10];
  const float* bo    = (const float*)d_in[11];
  const float* wg    = (const float*)d_in[12];
  const float* bg    = (const float*)d_in[13];
  const float* Av    = (const float*)d_in[14];
  const float* Bw    = (const float*)d_in[15];
  const float* Cw    = (const float*)d_in[16];
  const float* ln2_g = (const float*)d_in[17];
  const float* ln2_b = (const float*)d_in[18];
  const float* w1    = (const float*)d_in[19];
  const float* b1    = (const float*)d_in[20];
  const float* w2    = (const float*)d_in[21];
  const float* b2    = (const float*)d_in[22];

  char* p = (char*)d_ws;
  auto take = [&](size_t bytes) { char* q = p; p += (bytes + 255) & ~(size_t)255; return q; };
  unsigned short* WcatT  = (unsigned short*)take((size_t)LDQ * 1024 * 2);
  unsigned short* woT    = (unsigned short*)take((size_t)1024 * 1024 * 2);
  unsigned short* CwT    = (unsigned short*)take((size_t)1024 * 128 * 2);
  unsigned short* w1T    = (unsigned short*)take((size_t)4096 * 1024 * 2);
  unsigned short* w2T    = (unsigned short*)take((size_t)1024 * 4096 * 2);
  float*          bcat   = (float*)take((size_t)LDQ * 4);
  unsigned short* xn     = (unsigned short*)take((size_t)M_ROWS * 1024 * 2);
  unsigned short* qkvgu  = (unsigned short*)take((size_t)M_ROWS * LDQ * 2);
  unsigned short* VT     = (unsigned short*)take((size_t)BATCH * N_HEADS * 64 * T_LEN * 2);
  unsigned short* ao     = (unsigned short*)take((size_t)M_ROWS * 1024 * 2);
  unsigned short* states = (unsigned short*)take((size_t)M_ROWS * N_STATE * 2);
  unsigned short* attn_o = (unsigned short*)take((size_t)M_ROWS * 1024 * 2);
  unsigned short* ssm_o  = (unsigned short*)take((size_t)M_ROWS * 1024 * 2);
  unsigned short* hbuf   = qkvgu;   // alias: qkvgu dead after fusion

  float* outx = (float*)d_out;
  float* out_state = outx + (size_t)M_ROWS * 1024;

  // --- weight prep + LN1 (single launch) ---
  prep_kernel<<<17681, 256, 0, stream>>>(
      wq, wk, wv, wg, wo, Bw, Cw, w1, w2, bq, bk, bv, bg,
      x, ln1_g, ln1_b,
      WcatT, woT, CwT, w1T, w2T, bcat, xn);

  // --- forward ---
  gemm128ho<0, true><<<32 * 34, 256, 0, stream>>>(
      xn, WcatT, bcat, qkvgu, VT, LDQ, 1024, 34);
  attn_scan_kernel<<<dim3(66, 16, 2), 256, 0, stream>>>(
      qkvgu, VT, ao, Av, ssm0, states, out_state);
  gemm_dual<<<1024, 256, 0, stream>>>(
      ao, woT, bo, attn_o, 1024,
      states, CwT, nullptr, ssm_o, 128);
  fusion_ln2_kernel<<<4096, 256, 0, stream>>>(
      x, qkvgu, attn_o, ssm_o, ln2_g, ln2_b, outx, xn);
  gemm128ho<2, false><<<32 * 32, 256, 0, stream>>>(
      xn, w1T, b1, hbuf, nullptr, 4096, 1024, 32);
  gemm_ho<0, false, true><<<32 * 16, 256, 0, stream>>>(
      hbuf, w2T, b2, outx, outx, 1024, 4096, 32);
}